// Round 1
// baseline (74.522 us; speedup 1.0000x reference)
//
#include <hip/hip_runtime.h>

// Problem constants
// B=256, IN_F=512, K_INT=75, OUT_F=64
// Workspace layout: Mt[o][k][b] : ws[o*19200 + k*256 + b], 64*75*256*4 = 4,915,200 B

__global__ __launch_bounds__(256) void md_gemm(const float* __restrict__ x,
                                               const float* __restrict__ T,
                                               float* __restrict__ Mt) {
  const int kc = blockIdx.x;        // k index, 0..74
  const int b0 = blockIdx.y << 5;   // batch chunk base (32 per block)
  const int tid = threadIdx.x;

  __shared__ float xsT[64][32];     // [f_local][b_local]
  __shared__ float4 ts4[64 * 16];   // [f_local][o/4]  (row = 64 floats)

  const int bo = tid & 31;          // this thread's b offset
  const int og = tid >> 5;          // 0..7
  const int ob = og << 3;           // o base (8 o's per thread)

  float acc[8];
#pragma unroll
  for (int q = 0; q < 8; ++q) acc[q] = 0.0f;

  const float4* x4 = reinterpret_cast<const float4*>(x);
  const float4* T4 = reinterpret_cast<const float4*>(T);

  for (int fc = 0; fc < 8; ++fc) {
    const int f0 = fc << 6;
    // stage x^T chunk: 32 b x 64 f  (write transposed so compute reads are conflict-free)
    {
      const int r = tid & 31;
      const int c = tid >> 5;       // 0..7
#pragma unroll
      for (int h = 0; h < 2; ++h) {
        const int cc = c + (h << 3);                       // float4 col 0..15
        float4 v = x4[(b0 + r) * 128 + (f0 >> 2) + cc];    // x[b0+r][f0+4cc .. +3]
        xsT[cc * 4 + 0][r] = v.x;
        xsT[cc * 4 + 1][r] = v.y;
        xsT[cc * 4 + 2][r] = v.z;
        xsT[cc * 4 + 3][r] = v.w;
      }
    }
    // stage T chunk: 64 f x 64 o (fixed k = kc); T[f][k][o], row stride 4800
    {
      const int r2 = tid & 15;
      const int g = tid >> 4;       // 0..15
#pragma unroll
      for (int p = 0; p < 4; ++p) {
        const int ff = (g << 2) + p;
        ts4[ff * 16 + r2] = T4[(f0 + ff) * 1200 + kc * 16 + r2];
      }
    }
    __syncthreads();
#pragma unroll 8
    for (int ff = 0; ff < 64; ++ff) {
      const float xa = xsT[ff][bo];                 // broadcast-pair read
      const float4 t0 = ts4[ff * 16 + (og << 1)];   // wave-broadcast reads
      const float4 t1 = ts4[ff * 16 + (og << 1) + 1];
      acc[0] += xa * t0.x; acc[1] += xa * t0.y;
      acc[2] += xa * t0.z; acc[3] += xa * t0.w;
      acc[4] += xa * t1.x; acc[5] += xa * t1.y;
      acc[6] += xa * t1.z; acc[7] += xa * t1.w;
    }
    __syncthreads();
  }
  // coalesced store: lanes 0..31 write consecutive b for each o
#pragma unroll
  for (int q = 0; q < 8; ++q) {
    Mt[(ob + q) * 19200 + kc * 256 + b0 + bo] = acc[q];
  }
}

// One block per (o, 32-row i-chunk). All 256 rows of M[:, :, o] staged in LDS.
__global__ __launch_bounds__(256) void md_pairwise(const float* __restrict__ Mt,
                                                   float* __restrict__ out) {
  const int o = blockIdx.x;          // 0..63
  const int ibase = blockIdx.y << 5; // 32 i's per block
  const int tid = threadIdx.x;

  __shared__ float smem[256 * 76];   // Mo[b][k], k padded to 76 with a zero -> 77,824 B

  // load: Mt[o][k][b] contiguous 19200 floats = 4800 float4, coalesced
  const float4* src4 = reinterpret_cast<const float4*>(Mt + o * 19200);
  for (int idx4 = tid; idx4 < 4800; idx4 += 256) {
    const float4 v = src4[idx4];
    const float vv[4] = {v.x, v.y, v.z, v.w};
#pragma unroll
    for (int q = 0; q < 4; ++q) {
      const int idx = (idx4 << 2) + q;
      const int k = idx >> 8;        // idx / 256
      const int b = idx & 255;       // idx % 256
      smem[b * 76 + k] = vv[q];
    }
  }
  smem[tid * 76 + 75] = 0.0f;        // K-pad: |0-0| contributes nothing
  __syncthreads();

  const int io = tid & 31;           // which i in the chunk
  const int jg = tid >> 5;           // j-group 0..7 (32 j's each)
  const int i = ibase + io;

  // own row into registers: 19 float4 (row stride 76 floats = 304 B, 16B-aligned)
  const float4* mo4 = reinterpret_cast<const float4*>(smem);
  float4 ri[19];
#pragma unroll
  for (int c = 0; c < 19; ++c) ri[c] = mo4[i * 19 + c];

  float accum = 0.0f;
  for (int jj = 0; jj < 32; ++jj) {
    const int j = (jg << 5) + jj;
    const float4* rj = mo4 + j * 19;  // wave-broadcast (<=2 distinct addrs/wave)
    float dx = 0.f, dy = 0.f, dz = 0.f, dw = 0.f;
#pragma unroll
    for (int c = 0; c < 19; ++c) {
      const float4 vj = rj[c];
      dx += __builtin_fabsf(vj.x - ri[c].x);
      dy += __builtin_fabsf(vj.y - ri[c].y);
      dz += __builtin_fabsf(vj.z - ri[c].z);
      dw += __builtin_fabsf(vj.w - ri[c].w);
    }
    const float dist = (dx + dy) + (dz + dw);
    accum += __expf(-dist);           // j==i gives exp(0)=1, cancels the -1 exactly
  }
  __syncthreads();

  // reduce the 8 j-group partials per i
  float* red = smem;                  // reuse LDS
  red[(jg << 5) + io] = accum;
  __syncthreads();
  if (tid < 32) {
    float s = 0.f;
#pragma unroll
    for (int g = 0; g < 8; ++g) s += red[(g << 5) + tid];
    out[(ibase + tid) * 64 + o] = s - 1.0f;
  }
}

extern "C" void kernel_launch(void* const* d_in, const int* in_sizes, int n_in,
                              void* d_out, int out_size, void* d_ws, size_t ws_size,
                              hipStream_t stream) {
  const float* x = (const float*)d_in[0];   // [256,512]
  const float* T = (const float*)d_in[1];   // [512,75,64]
  float* out = (float*)d_out;               // [256,64]
  float* Mt = (float*)d_ws;                 // [64][75][256] = 4,915,200 B

  md_gemm<<<dim3(75, 8), 256, 0, stream>>>(x, T, Mt);
  md_pairwise<<<dim3(64, 8), 256, 0, stream>>>(Mt, out);
}